// Round 7
// baseline (363.558 us; speedup 1.0000x reference)
//
#include <hip/hip_runtime.h>

typedef unsigned short u16;
typedef unsigned int u32;

#define S 2048
#define HID 2048
#define NH 16
#define NKV 4
#define D 128
#define QKVP 3072  // QKV buffer pitch (Q|K|V concat per row)
#define SCALE 0.08838834764831845f  // 1/sqrt(128)
#define NEG_INF -3.0e38f

typedef __attribute__((ext_vector_type(8))) short short8;  // 8 bf16 = 4 VGPRs
typedef __attribute__((ext_vector_type(4))) float f32x4;

__device__ __forceinline__ float bf2f(u16 u) {
  union { u32 i; float f; } c; c.i = ((u32)u) << 16; return c.f;
}
__device__ __forceinline__ u16 f2bf(float f) {
  union { float f; u32 i; } c; c.f = f;
  u32 x = c.i;
  u32 r = x + 0x7fffu + ((x >> 16) & 1u);  // RNE
  return (u16)(r >> 16);
}

__device__ __forceinline__ void gload16(const u16* g, u16* l) {
  __builtin_amdgcn_global_load_lds(
      (const __attribute__((address_space(1))) u32*)g,
      (__attribute__((address_space(3))) u32*)l, 16, 0, 0);
}

// ---------------- f32 -> bf16 elementwise convert ---------------------------
__global__ __launch_bounds__(256) void k_cvt(const float* __restrict__ src,
                                             u16* __restrict__ dst) {
  int i = (blockIdx.x * 256 + threadIdx.x) * 8;
  float4 v0 = *(const float4*)(src + i);
  float4 v1 = *(const float4*)(src + i + 4);
  ushort4 w0, w1;
  w0.x = f2bf(v0.x); w0.y = f2bf(v0.y); w0.z = f2bf(v0.z); w0.w = f2bf(v0.w);
  w1.x = f2bf(v1.x); w1.y = f2bf(v1.y); w1.z = f2bf(v1.z); w1.w = f2bf(v1.w);
  *(ushort4*)(dst + i) = w0;
  *(ushort4*)(dst + i + 4) = w1;
}

// ------- transpose + convert body: src[K][N] f32 -> dst[N][K] bf16 ----------
__device__ __forceinline__ void transpose_body(const float* __restrict__ src,
                                               u16* __restrict__ dst,
                                               int N, int K, int nt, int kt,
                                               int t) {
  __shared__ float T[64][65];
#pragma unroll
  for (int it = 0; it < 4; ++it) {
    int r = it * 16 + (t >> 4), c = (t & 15) * 4;
    float4 v = *(const float4*)(src + (size_t)(kt + r) * N + nt + c);
    T[r][c] = v.x; T[r][c + 1] = v.y; T[r][c + 2] = v.z; T[r][c + 3] = v.w;
  }
  __syncthreads();
#pragma unroll
  for (int it = 0; it < 2; ++it) {
    int n = it * 32 + (t >> 3), k8 = (t & 7) * 8;
    ushort4 w0, w1;
    w0.x = f2bf(T[k8 + 0][n]); w0.y = f2bf(T[k8 + 1][n]);
    w0.z = f2bf(T[k8 + 2][n]); w0.w = f2bf(T[k8 + 3][n]);
    w1.x = f2bf(T[k8 + 4][n]); w1.y = f2bf(T[k8 + 5][n]);
    w1.z = f2bf(T[k8 + 6][n]); w1.w = f2bf(T[k8 + 7][n]);
    *(ushort4*)(dst + (size_t)(nt + n) * K + kt + k8) = w0;
    *(ushort4*)(dst + (size_t)(nt + n) * K + kt + k8 + 4) = w1;
  }
}

__global__ __launch_bounds__(256) void k_transpose(const float* __restrict__ src,
                                                   u16* __restrict__ dst,
                                                   int N, int K) {
  transpose_body(src, dst, N, K, blockIdx.x * 64, blockIdx.y * 64, threadIdx.x);
}

__global__ __launch_bounds__(256) void k_transpose_qkv(const float* __restrict__ Wq,
                                                       const float* __restrict__ Wk,
                                                       const float* __restrict__ Wv,
                                                       u16* __restrict__ WT) {
  const int bx = blockIdx.x;
  const float* src; u16* dst; int N, nt;
  if (bx < 32)      { src = Wq; dst = WT;                    N = 2048; nt = bx * 64; }
  else if (bx < 40) { src = Wk; dst = WT + 2048ull * 2048;   N = 512;  nt = (bx - 32) * 64; }
  else              { src = Wv; dst = WT + 2560ull * 2048;   N = 512;  nt = (bx - 40) * 64; }
  transpose_body(src, dst, N, 2048, nt, blockIdx.y * 64, threadIdx.x);
}

// ------- V transpose: QKV V-section [s][2560+gd] bf16 -> Vt[gd][s] bf16 -----
__global__ __launch_bounds__(256) void k_vt(const u16* __restrict__ QKV,
                                            u16* __restrict__ Vt) {
  __shared__ u16 T[64][66];
  const int t = threadIdx.x;
  const int s0 = blockIdx.x * 64, d0 = blockIdx.y * 64;
#pragma unroll
  for (int it = 0; it < 4; ++it) {
    int r = it * 16 + (t >> 4), c = (t & 15) * 4;
    ushort4 v = *(const ushort4*)(QKV + (size_t)(s0 + r) * QKVP + 2560 + d0 + c);
    T[r][c] = v.x; T[r][c + 1] = v.y; T[r][c + 2] = v.z; T[r][c + 3] = v.w;
  }
  __syncthreads();
#pragma unroll
  for (int it = 0; it < 4; ++it) {
    int dd = it * 16 + (t >> 4), sc = (t & 15) * 4;
    ushort4 w;
    w.x = T[sc + 0][dd]; w.y = T[sc + 1][dd];
    w.z = T[sc + 2][dd]; w.w = T[sc + 3][dd];
    *(ushort4*)(Vt + (size_t)(d0 + dd) * S + s0 + sc) = w;
  }
}

// ---------------- MFMA GEMM, double-buffered DMA (1 barrier / k-iter) -------
__global__ __launch_bounds__(256) void k_gemm_mfma(const u16* __restrict__ A,
                                                   const u16* __restrict__ BT,
                                                   void* __restrict__ Cout,
                                                   int N, int K, int out_bf16) {
  __shared__ __align__(16) u16 As[2][128 * 32];
  __shared__ __align__(16) u16 Bs[2][128 * 32];
  const int t = threadIdx.x, w = t >> 6, lane = t & 63;
  const int l15 = lane & 15, quad = lane >> 4;
  const int m0 = blockIdx.y * 128, n0 = blockIdx.x * 128;
  const int wr = w >> 1, wc = w & 1;

  const int sr = w * 16 + (lane >> 2);
  const int sk8 = (lane & 3) * 8;
  const u16* Ag0 = A + (size_t)(m0 + sr) * K + sk8;
  const u16* Ag1 = A + (size_t)(m0 + 64 + sr) * K + sk8;
  const u16* Bg0 = BT + (size_t)(n0 + sr) * K + sk8;
  const u16* Bg1 = BT + (size_t)(n0 + 64 + sr) * K + sk8;

  f32x4 acc[4][4];
#pragma unroll
  for (int i = 0; i < 4; ++i)
#pragma unroll
    for (int j = 0; j < 4; ++j) acc[i][j] = (f32x4){0.f, 0.f, 0.f, 0.f};

  // prologue: stage k=0 into buf 0
  gload16(Ag0, &As[0][w * 512]);
  gload16(Ag1, &As[0][2048 + w * 512]);
  gload16(Bg0, &Bs[0][w * 512]);
  gload16(Bg1, &Bs[0][2048 + w * 512]);

  const int nk = K >> 5;
  for (int ki = 0; ki < nk; ++ki) {
    const int cur = ki & 1;
    __syncthreads();  // drains DMA(cur); all reads of cur^1 from prev iter done
    if (ki + 1 < nk) {  // stage next tile; drains at NEXT barrier (post-compute)
      const int kn = (ki + 1) << 5;
      gload16(Ag0 + kn, &As[cur ^ 1][w * 512]);
      gload16(Ag1 + kn, &As[cur ^ 1][2048 + w * 512]);
      gload16(Bg0 + kn, &Bs[cur ^ 1][w * 512]);
      gload16(Bg1 + kn, &Bs[cur ^ 1][2048 + w * 512]);
    }
    short8 af[4], bf[4];
#pragma unroll
    for (int i = 0; i < 4; ++i)
      af[i] = *(const short8*)&As[cur][(wr * 64 + i * 16 + l15) * 32 + quad * 8];
#pragma unroll
    for (int j = 0; j < 4; ++j)
      bf[j] = *(const short8*)&Bs[cur][(wc * 64 + j * 16 + l15) * 32 + quad * 8];
#pragma unroll
    for (int i = 0; i < 4; ++i)
#pragma unroll
      for (int j = 0; j < 4; ++j)
        acc[i][j] = __builtin_amdgcn_mfma_f32_16x16x32_bf16(af[i], bf[j], acc[i][j], 0, 0, 0);
  }

  if (out_bf16) {
    u16* C = (u16*)Cout;
#pragma unroll
    for (int i = 0; i < 4; ++i)
#pragma unroll
      for (int j = 0; j < 4; ++j) {
        int col = n0 + wc * 64 + j * 16 + l15;
#pragma unroll
        for (int r = 0; r < 4; ++r)
          C[(size_t)(m0 + wr * 64 + i * 16 + quad * 4 + r) * N + col] = f2bf(acc[i][j][r]);
      }
  } else {
    float* C = (float*)Cout;
#pragma unroll
    for (int i = 0; i < 4; ++i)
#pragma unroll
      for (int j = 0; j < 4; ++j) {
        int col = n0 + wc * 64 + j * 16 + l15;
#pragma unroll
        for (int r = 0; r < 4; ++r)
          C[(size_t)(m0 + wr * 64 + i * 16 + quad * 4 + r) * N + col] = acc[i][j][r];
      }
  }
}

// ------------- per-(s,head) RMSNorm + RoPE, Q and K in one launch -----------
__global__ __launch_bounds__(128) void k_norm_rope(u16* __restrict__ QKV,
                                                   const float* __restrict__ qsc,
                                                   const float* __restrict__ ksc,
                                                   const float* __restrict__ cosp,
                                                   const float* __restrict__ sinp) {
  const int s = blockIdx.x, hh = blockIdx.y, d = threadIdx.x;
  u16* row; const float* sc; float scale;
  if (hh < NH) { row = QKV + (size_t)s * QKVP + hh * D;            sc = qsc; scale = SCALE; }
  else         { row = QKV + (size_t)s * QKVP + 2048 + (hh - NH) * D; sc = ksc; scale = 1.0f; }
  float x = bf2f(row[d]);
  float v = x * x;
#pragma unroll
  for (int o = 32; o; o >>= 1) v += __shfl_xor(v, o, 64);
  __shared__ float red[2];
  if ((d & 63) == 0) red[d >> 6] = v;
  __syncthreads();
  float var = (red[0] + red[1]) * (1.0f / 128.0f);
  float rinv = rsqrtf(var + 1e-6f) * scale;
  float xn = x * rinv * sc[d];
  __shared__ float sh[D];
  sh[d] = xn;
  __syncthreads();
  float rot = (d < 64) ? -sh[d + 64] : sh[d - 64];
  row[d] = f2bf(xn * cosp[s * D + d] + rot * sinp[s * D + d]);
}

// ---------------- flash attention v4 ----------------------------------------
// Manual K/V staging (pitches 136/72 u16 — both !=0 mod 32 dwords; the R5 DMA
// forced 256B rows whose bank shift is 0 -> ~8-way conflicts). Register
// prefetch of tile jt+1 issued before COMPUTE(jt): the vmcnt drain at the next
// barrier lands after a full compute phase. Heavy-first grid (NH, 32).
#define KP 136   // K row pitch (u16): 272 B, 16B-aligned b128 frags
#define VP 72    // V row pitch (u16): 144 B, 16B-aligned
#define PTP 72   // P pitch (u16)

__global__ __launch_bounds__(256) void k_flash(const u16* __restrict__ QKV,
                                               const u16* __restrict__ Vt,
                                               u16* __restrict__ O) {
  const int qt = 31 - (int)blockIdx.y;  // heaviest blocks of ALL heads first
  const int h = blockIdx.x, g = h >> 2;
  const int t = threadIdx.x;
  const int w = t >> 6, lane = t & 63, l15 = lane & 15, quad = lane >> 4;

  __shared__ __align__(16) u16 Klds[64 * KP];   // 17.0 KB
  __shared__ __align__(16) u16 Vlds[128 * VP];  // 18.0 KB [d][key] swizzled
  __shared__ __align__(16) u16 Pt[4][16 * PTP]; //  9.0 KB

  const int qbase = qt * 64 + w * 16;
  const int qrow = qbase + l15;

  short8 qf[4];
  {
    const u16* qp = QKV + (size_t)qrow * QKVP + h * D + quad * 8;
#pragma unroll
    for (int c = 0; c < 4; ++c) qf[c] = *(const short8*)(qp + c * 32);
  }

  float m = NEG_INF, l = 0.f;
  f32x4 oacc[8];
#pragma unroll
  for (int nc = 0; nc < 8; ++nc) oacc[nc] = (f32x4){0.f, 0.f, 0.f, 0.f};

  const int nt = qt + 1;
  const int kr_row = t >> 4, kr_c = t & 15;  // K staging coords (16 thr/row)
  const int vr_row = t >> 3, vr_c = t & 7;   // V staging coords (8 thr/row)

  uint4 kr[4], vr[4];
  auto KVLOAD = [&](int j0) {
#pragma unroll
    for (int it = 0; it < 4; ++it)
      kr[it] = *(const uint4*)(QKV + (size_t)(j0 + kr_row + it * 16) * QKVP +
                               2048 + g * D + kr_c * 8);
#pragma unroll
    for (int it = 0; it < 4; ++it)
      vr[it] = *(const uint4*)(Vt + (size_t)(g * D + vr_row + it * 32) * S +
                               j0 + vr_c * 8);
  };
  auto KVWRITE = [&]() {
#pragma unroll
    for (int it = 0; it < 4; ++it)
      *(uint4*)&Klds[(kr_row + it * 16) * KP + kr_c * 8] = kr[it];
#pragma unroll
    for (int it = 0; it < 4; ++it) {
      int d = vr_row + it * 32;
      *(uint4*)&Vlds[d * VP + ((vr_c ^ (d & 7)) * 8)] = vr[it];
    }
  };

  KVLOAD(0);
  for (int jt = 0; jt < nt; ++jt) {
    const int j0 = jt * 64;
    __syncthreads();  // prev tile's LDS reads done
    KVWRITE();
    __syncthreads();  // staged tile visible
    if (jt + 1 < nt) KVLOAD(j0 + 64);  // in flight during compute below

    // ---- S^T = K x Q^T : row = key, col = q-row (l15) ----
    f32x4 sa[4];
#pragma unroll
    for (int sub = 0; sub < 4; ++sub) {
      f32x4 acc = {0.f, 0.f, 0.f, 0.f};
#pragma unroll
      for (int c = 0; c < 4; ++c) {
        short8 kf = *(const short8*)&Klds[(sub * 16 + l15) * KP + c * 32 + quad * 8];
        acc = __builtin_amdgcn_mfma_f32_16x16x32_bf16(kf, qf[c], acc, 0, 0, 0);
      }
      sa[sub] = acc;
    }
    if (jt == nt - 1) {  // causal mask, diagonal tile only
#pragma unroll
      for (int sub = 0; sub < 4; ++sub) {
        int keyb = j0 + sub * 16 + quad * 4;
#pragma unroll
        for (int r = 0; r < 4; ++r)
          if (keyb + r > qrow) sa[sub][r] = NEG_INF;
      }
    }
    // ---- online softmax (per-lane state, 2 cross-quad shfl per reduce) ----
    float tmax = sa[0][0];
#pragma unroll
    for (int sub = 0; sub < 4; ++sub)
#pragma unroll
      for (int r = 0; r < 4; ++r) tmax = fmaxf(tmax, sa[sub][r]);
    tmax = fmaxf(tmax, __shfl_xor(tmax, 16, 64));
    tmax = fmaxf(tmax, __shfl_xor(tmax, 32, 64));
    float mn = fmaxf(m, tmax);
    float alpha = __expf(m - mn);
    m = mn;
    float rs = 0.f;
#pragma unroll
    for (int sub = 0; sub < 4; ++sub) {
      float p0 = __expf(sa[sub][0] - m);
      float p1 = __expf(sa[sub][1] - m);
      float p2 = __expf(sa[sub][2] - m);
      float p3 = __expf(sa[sub][3] - m);
      rs += (p0 + p1) + (p2 + p3);
      u32 lo = (u32)f2bf(p0) | ((u32)f2bf(p1) << 16);
      u32 hi = (u32)f2bf(p2) | ((u32)f2bf(p3) << 16);
      *(uint2*)&Pt[w][l15 * PTP + sub * 16 + quad * 4] = make_uint2(lo, hi);
    }
    rs += __shfl_xor(rs, 16, 64);
    rs += __shfl_xor(rs, 32, 64);
    l = l * alpha + rs;
#pragma unroll
    for (int nc = 0; nc < 8; ++nc) {
      oacc[nc][0] *= alpha; oacc[nc][1] *= alpha;
      oacc[nc][2] *= alpha; oacc[nc][3] *= alpha;
    }
    // ---- O^T += V^T x P^T ----
#pragma unroll
    for (int kc = 0; kc < 2; ++kc) {
      short8 pf = *(const short8*)&Pt[w][l15 * PTP + kc * 32 + quad * 8];
#pragma unroll
      for (int nc = 0; nc < 8; ++nc) {
        int d = nc * 16 + l15;
        short8 vf = *(const short8*)&Vlds[d * VP + (((kc * 4 + quad) ^ (d & 7)) * 8)];
        oacc[nc] = __builtin_amdgcn_mfma_f32_16x16x32_bf16(vf, pf, oacc[nc], 0, 0, 0);
      }
    }
  }

  // ---- epilogue: O[q][d] = O^T / l ----
  float inv = 1.0f / l;
  u16* orow = O + (size_t)qrow * HID + h * D;
#pragma unroll
  for (int nc = 0; nc < 8; ++nc) {
    ushort4 wv;
    wv.x = f2bf(oacc[nc][0] * inv); wv.y = f2bf(oacc[nc][1] * inv);
    wv.z = f2bf(oacc[nc][2] * inv); wv.w = f2bf(oacc[nc][3] * inv);
    *(ushort4*)(orow + nc * 16 + quad * 4) = wv;
  }
}

// ---------------- final RMSNorm over HIDDEN=2048 ----------------------------
__device__ __forceinline__ float blockSum256(float v, float* red, int t) {
#pragma unroll
  for (int o = 32; o; o >>= 1) v += __shfl_xor(v, o, 64);
  if ((t & 63) == 0) red[t >> 6] = v;
  __syncthreads();
  v = red[0] + red[1] + red[2] + red[3];
  __syncthreads();
  return v;
}

__global__ __launch_bounds__(256) void k_fnorm(const float* __restrict__ X,
                                               const float* __restrict__ sc,
                                               float* __restrict__ out) {
  const int s = blockIdx.x, t = threadIdx.x;
  const float* row = X + (size_t)s * HID;
  float4 r0 = *(const float4*)(row + t * 8);
  float4 r1 = *(const float4*)(row + t * 8 + 4);
  float x[8] = {r0.x, r0.y, r0.z, r0.w, r1.x, r1.y, r1.z, r1.w};
  float ss = 0.f;
#pragma unroll
  for (int ii = 0; ii < 8; ++ii) ss += x[ii] * x[ii];
  __shared__ float red[4];
  float tot = blockSum256(ss, red, t);
  float rinv = rsqrtf(tot * (1.0f / 2048.0f) + 1e-6f);
  float4 s0 = *(const float4*)(sc + t * 8);
  float4 s1 = *(const float4*)(sc + t * 8 + 4);
  float4 w0 = make_float4(x[0] * rinv * s0.x, x[1] * rinv * s0.y,
                          x[2] * rinv * s0.z, x[3] * rinv * s0.w);
  float4 w1 = make_float4(x[4] * rinv * s1.x, x[5] * rinv * s1.y,
                          x[6] * rinv * s1.z, x[7] * rinv * s1.w);
  *(float4*)(out + (size_t)s * HID + t * 8) = w0;
  *(float4*)(out + (size_t)s * HID + t * 8 + 4) = w1;
}

extern "C" void kernel_launch(void* const* d_in, const int* in_sizes, int n_in,
                              void* d_out, int out_size, void* d_ws, size_t ws_size,
                              hipStream_t stream) {
  const float* hidden = (const float*)d_in[0];
  const float* cosp   = (const float*)d_in[1];
  const float* sinp   = (const float*)d_in[2];
  const float* Wq     = (const float*)d_in[3];
  const float* Wk     = (const float*)d_in[4];
  const float* Wv     = (const float*)d_in[5];
  const float* Wo     = (const float*)d_in[6];
  const float* qsc    = (const float*)d_in[7];
  const float* ksc    = (const float*)d_in[8];
  const float* lsc    = (const float*)d_in[9];
  float* out = (float*)d_out;

  char* ws = (char*)d_ws;
  u16*   Hb  = (u16*)(ws);                   // [S][HID] bf16, 8 MiB
  u16*   WoT = (u16*)(ws);                   // overlays Hb (after QKV GEMM)
  u16*   WT  = (u16*)(ws + (8ull << 20));    // [3072][2048] bf16, 12 MiB
  u16*   An  = (u16*)(ws + (8ull << 20));    // overlays WT (after QKV GEMM)
  u16*   QKV = (u16*)(ws + (20ull << 20));   // [S][3072] bf16, 12 MiB
  float* Ob  = (float*)(ws + (20ull << 20)); // overlays QKV (after flash)
  u16*   Vtb = (u16*)(ws + (32ull << 20));   // [512][2048] bf16, 2 MiB

  k_cvt<<<S * HID / (256 * 8), 256, 0, stream>>>(hidden, Hb);
  k_transpose_qkv<<<dim3(48, 32), 256, 0, stream>>>(Wq, Wk, Wv, WT);
  k_gemm_mfma<<<dim3(24, 16), 256, 0, stream>>>(Hb, WT, QKV, QKVP, 2048, 1);
  k_transpose<<<dim3(32, 32), 256, 0, stream>>>(Wo, WoT, 2048, 2048);  // Hb dead
  k_norm_rope<<<dim3(S, NH + NKV), 128, 0, stream>>>(QKV, qsc, ksc, cosp, sinp);
  k_vt<<<dim3(32, 8), 256, 0, stream>>>(QKV, Vtb);
  k_flash<<<dim3(NH, 32), 256, 0, stream>>>(QKV, Vtb, An);
  k_gemm_mfma<<<dim3(16, 16), 256, 0, stream>>>(An, WoT, Ob, 2048, 2048, 0);
  k_fnorm<<<S, 256, 0, stream>>>(Ob, lsc, out);
}